// Round 2
// baseline (495.733 us; speedup 1.0000x reference)
//
#include <hip/hip_runtime.h>
#include <math.h>

#define BATCH 32
#define NH 32
#define NKVH 8
#define GRP 4
#define HD 128
#define BLKSZ 16
#define MAXB 128
#define PART 128
#define NPART 16
#define SCALE 0.08838834764831845f
#define NEGINF (-1e30f)

// ws layout (float elements):
#define WS_QROT 0                                     // B*NH*HD = 131072 (q roped, pre-scaled)
#define WS_KROT (BATCH*NH*HD)                         // +B*KVH*HD = 32768 (new k roped, unscaled)
#define WS_ML   (WS_KROT + BATCH*NKVH*HD)             // +B*KVH*G*NPART*2 = 32768
#define WS_OP   (WS_ML + BATCH*NKVH*GRP*NPART*2)      // +B*KVH*G*NPART*HD = 2097152

// Native clang vector types: __builtin_nontemporal_load requires these
// (HIP_vector_type structs are rejected by the builtin).
typedef float f32x4 __attribute__((ext_vector_type(4)));
typedef float f32x2 __attribute__((ext_vector_type(2)));

// Single-use KV stream: bypass L2 retention with non-temporal loads.
__device__ __forceinline__ f32x4 ldnt4(const float* p) {
    return __builtin_nontemporal_load((const f32x4*)p);
}
__device__ __forceinline__ f32x2 ldnt2(const float* p) {
    return __builtin_nontemporal_load((const f32x2*)p);
}

// ---- prep: rope q -> ws (pre-scaled), rope new-k -> ws (unscaled).
//      NO writes to k_cache / v_cache: kernel is pure-read on all inputs,
//      so the harness has nothing to restore between iterations. ----
__global__ __launch_bounds__(128)
void prep(const float* __restrict__ q,
          const float* __restrict__ nk,
          const int* __restrict__ ctx,
          float* __restrict__ ws) {
    int b = blockIdx.x;
    int t = threadIdx.x;                 // 0..127, covers d
    int L = ctx[b];
    __shared__ float cs[64], sn[64];
    if (t < 64) {
        double f = pow(10000.0, -(double)t / 64.0);
        double a = (double)L * f;        // pos = context_lens per reference
        cs[t] = (float)cos(a);
        sn[t] = (float)sin(a);
    }
    __syncthreads();
    float c = cs[t & 63], s = sn[t & 63];
    for (int h = 0; h < NH; ++h) {
        const float* qp = q + ((size_t)b * NH + h) * HD;
        float x = qp[t], y = qp[t ^ 64];
        float r = (t < 64) ? (x * c - y * s) : (x * c + y * s);
        ws[WS_QROT + ((size_t)b * NH + h) * HD + t] = r * SCALE;
    }
    for (int kh = 0; kh < NKVH; ++kh) {
        const float* kp = nk + ((size_t)b * NKVH + kh) * HD;
        float x = kp[t], y = kp[t ^ 64];
        float r = (t < 64) ? (x * c - y * s) : (x * c + y * s);
        ws[WS_KROT + ((size_t)b * NKVH + kh) * HD + t] = r;
    }
}

// ---- attn: streaming flash-decode partial. Tokens 0..L-2 come from the
//      (untouched) caches; token L-1 is patched in from ws/new_v. ----
__global__ __launch_bounds__(256)
void attn(const float* __restrict__ kc,
          const float* __restrict__ vc,
          const float* __restrict__ nv,
          const int* __restrict__ ctx,
          const int* __restrict__ btab,
          float* __restrict__ ws)
{
    int part = blockIdx.x, kvh = blockIdx.y, b = blockIdx.z;
    int L = ctx[b];
    int start = part * PART;
    if (start >= L) return;              // reducer skips unwritten partitions
    int end = min(start + PART, L);
    int n = end - start;
    bool hasNew = (end == L);            // this partition owns token L-1
    int endC = end - (hasNew ? 1 : 0);   // cache-backed token range [start, endC)

    int tid = threadIdx.x;
    int hw = tid >> 5;                   // half-wave 0..7
    int hl = tid & 31;                   // lane in half-wave: d = 4*hl..4*hl+3
    int wave = tid >> 6, lane = tid & 63;

    __shared__ int   bts[PART / BLKSZ];  // 8 block ids
    __shared__ float qs[GRP][HD];        // roped+scaled q, 2 KB
    __shared__ float sc[GRP][PART];      // scores -> probs, 2 KB
    __shared__ float oacc[4][GRP][HD];   // per-wave partial outputs, 8 KB

    if (tid < PART / BLKSZ)
        bts[tid] = btab[b * MAXB + (start >> 4) + tid];
    {   // 512 floats, 256 threads x float2
        const float* qrot = ws + WS_QROT + ((size_t)b * NH + kvh * GRP) * HD;
        ((float2*)&qs[0][0])[tid] = ((const float2*)qrot)[tid];
    }
    __syncthreads();

    float4 qa[GRP];
#pragma unroll
    for (int g = 0; g < GRP; ++g)
        qa[g] = *(const float4*)(&qs[g][4 * hl]);

    const size_t koff = (size_t)kvh * HD + 4 * hl;

    // ---- Phase 1: scores from cache; 4 tokens (4 x 512B loads) in flight per half-wave ----
    int i = start + hw;
    for (; i + 24 < endC; i += 32) {
        int s0 = i, s1 = i + 8, s2 = i + 16, s3 = i + 24;
        f32x4 k0 = ldnt4(kc + ((size_t)bts[(s0 - start) >> 4] << 14) + ((s0 & 15) << 10) + koff);
        f32x4 k1 = ldnt4(kc + ((size_t)bts[(s1 - start) >> 4] << 14) + ((s1 & 15) << 10) + koff);
        f32x4 k2 = ldnt4(kc + ((size_t)bts[(s2 - start) >> 4] << 14) + ((s2 & 15) << 10) + koff);
        f32x4 k3 = ldnt4(kc + ((size_t)bts[(s3 - start) >> 4] << 14) + ((s3 & 15) << 10) + koff);
        float p0[GRP], p1[GRP], p2[GRP], p3[GRP];
#pragma unroll
        for (int g = 0; g < GRP; ++g) {
            p0[g] = qa[g].x * k0.x + qa[g].y * k0.y + qa[g].z * k0.z + qa[g].w * k0.w;
            p1[g] = qa[g].x * k1.x + qa[g].y * k1.y + qa[g].z * k1.z + qa[g].w * k1.w;
            p2[g] = qa[g].x * k2.x + qa[g].y * k2.y + qa[g].z * k2.z + qa[g].w * k2.w;
            p3[g] = qa[g].x * k3.x + qa[g].y * k3.y + qa[g].z * k3.z + qa[g].w * k3.w;
        }
#pragma unroll
        for (int off = 16; off >= 1; off >>= 1) {
#pragma unroll
            for (int g = 0; g < GRP; ++g) {
                p0[g] += __shfl_xor(p0[g], off, 32);
                p1[g] += __shfl_xor(p1[g], off, 32);
                p2[g] += __shfl_xor(p2[g], off, 32);
                p3[g] += __shfl_xor(p3[g], off, 32);
            }
        }
        if (hl == 0) {
#pragma unroll
            for (int g = 0; g < GRP; ++g) {
                sc[g][s0 - start] = p0[g];
                sc[g][s1 - start] = p1[g];
                sc[g][s2 - start] = p2[g];
                sc[g][s3 - start] = p3[g];
            }
        }
    }
    for (; i < endC; i += 8) {
        f32x4 k0 = ldnt4(kc + ((size_t)bts[(i - start) >> 4] << 14) + ((i & 15) << 10) + koff);
        float p0[GRP];
#pragma unroll
        for (int g = 0; g < GRP; ++g)
            p0[g] = qa[g].x * k0.x + qa[g].y * k0.y + qa[g].z * k0.z + qa[g].w * k0.w;
#pragma unroll
        for (int off = 16; off >= 1; off >>= 1)
#pragma unroll
            for (int g = 0; g < GRP; ++g)
                p0[g] += __shfl_xor(p0[g], off, 32);
        if (hl == 0)
#pragma unroll
            for (int g = 0; g < GRP; ++g)
                sc[g][i - start] = p0[g];
    }

    // ---- New-token score patch: sc[g][n-1] = qs[g] . rope(new_k). Wave g owns head g. ----
    if (hasNew) {
        int g = wave;
        const float* kn = ws + WS_KROT + ((size_t)b * NKVH + kvh) * HD;
        float2 kv = *(const float2*)(kn + 2 * lane);
        float2 qv = *(const float2*)(&qs[g][2 * lane]);
        float p = qv.x * kv.x + qv.y * kv.y;
#pragma unroll
        for (int off = 32; off >= 1; off >>= 1) p += __shfl_xor(p, off);
        if (lane == 0) sc[g][n - 1] = p;
    }
    __syncthreads();

    // ---- Phase 2: per-head softmax (unnormalized), wave w owns head w ----
    {
        int g = wave;
        float m = NEGINF;
        for (int j = lane; j < n; j += 64) m = fmaxf(m, sc[g][j]);
#pragma unroll
        for (int off = 32; off >= 1; off >>= 1) m = fmaxf(m, __shfl_xor(m, off));
        float sum = 0.f;
        for (int j = lane; j < n; j += 64) {
            float e = __expf(sc[g][j] - m);
            sc[g][j] = e;
            sum += e;
        }
#pragma unroll
        for (int off = 32; off >= 1; off >>= 1) sum += __shfl_xor(sum, off);
        if (lane == 0) {
            size_t mlidx = ((((size_t)b * NKVH + kvh) * GRP + g) * NPART + part) * 2;
            ws[WS_ML + mlidx]     = m;
            ws[WS_ML + mlidx + 1] = sum;
        }
    }
    __syncthreads();

    // ---- Phase 3: o += p[s]*V[s] over cache tokens; wave owns a contiguous
    //      64-token chunk, float2 per lane, 4 x 512B loads in flight ----
    float2 acc[GRP];
#pragma unroll
    for (int g = 0; g < GRP; ++g) acc[g] = make_float2(0.f, 0.f);

    const size_t voff = (size_t)kvh * HD + 2 * lane;
    int t0 = start + (wave << 6);
    int tend = min(t0 + 64, endC);
    int t = t0;
    for (; t + 3 < tend; t += 4) {
        f32x2 v0 = ldnt2(vc + ((size_t)bts[(t     - start) >> 4] << 14) + (( t      & 15) << 10) + voff);
        f32x2 v1 = ldnt2(vc + ((size_t)bts[(t + 1 - start) >> 4] << 14) + (((t + 1) & 15) << 10) + voff);
        f32x2 v2 = ldnt2(vc + ((size_t)bts[(t + 2 - start) >> 4] << 14) + (((t + 2) & 15) << 10) + voff);
        f32x2 v3 = ldnt2(vc + ((size_t)bts[(t + 3 - start) >> 4] << 14) + (((t + 3) & 15) << 10) + voff);
#pragma unroll
        for (int g = 0; g < GRP; ++g) {
            float4 e = *(const float4*)(&sc[g][t - start]);   // (t-start) % 4 == 0
            acc[g].x += e.x * v0.x; acc[g].y += e.x * v0.y;
            acc[g].x += e.y * v1.x; acc[g].y += e.y * v1.y;
            acc[g].x += e.z * v2.x; acc[g].y += e.z * v2.y;
            acc[g].x += e.w * v3.x; acc[g].y += e.w * v3.y;
        }
    }
    for (; t < tend; ++t) {
        f32x2 v0 = ldnt2(vc + ((size_t)bts[(t - start) >> 4] << 14) + ((t & 15) << 10) + voff);
#pragma unroll
        for (int g = 0; g < GRP; ++g) {
            float e = sc[g][t - start];
            acc[g].x += e * v0.x; acc[g].y += e * v0.y;
        }
    }
    // ---- New-token V patch: acc += p[L-1] * new_v, on the wave owning that chunk ----
    if (hasNew && wave == ((n - 1) >> 6)) {
        float2 v = *(const float2*)(nv + ((size_t)b * NKVH + kvh) * HD + 2 * lane);
#pragma unroll
        for (int g = 0; g < GRP; ++g) {
            float e = sc[g][n - 1];
            acc[g].x += e * v.x; acc[g].y += e * v.y;
        }
    }
#pragma unroll
    for (int g = 0; g < GRP; ++g)
        *(float2*)&oacc[wave][g][2 * lane] = acc[g];
    __syncthreads();

    for (int o = tid; o < GRP * HD; o += 256) {
        int g = o >> 7, d = o & 127;
        float ssum = oacc[0][g][d] + oacc[1][g][d] + oacc[2][g][d] + oacc[3][g][d];
        ws[WS_OP + ((((size_t)b * NKVH + kvh) * GRP + g) * NPART + part) * HD + d] = ssum;
    }
}

__global__ __launch_bounds__(128)
void attn_reduce(const int* __restrict__ ctx,
                 const float* __restrict__ ws,
                 float* __restrict__ out) {
    int bh = blockIdx.x;
    int b = bh >> 5;
    int h = bh & 31;
    int kvh = h >> 2, g = h & 3;
    int L = ctx[b];
    int np = min(NPART, (L + PART - 1) / PART);
    size_t base = (((size_t)b * NKVH + kvh) * GRP + g) * NPART;
    float M = NEGINF;
    for (int p = 0; p < np; ++p)
        M = fmaxf(M, ws[WS_ML + (base + p) * 2]);
    float w_[NPART];
    float Lsum = 0.f;
    for (int p = 0; p < np; ++p) {
        float e = __expf(ws[WS_ML + (base + p) * 2] - M);
        w_[p] = e;
        Lsum += e * ws[WS_ML + (base + p) * 2 + 1];
    }
    float inv = 1.0f / Lsum;
    int d = threadIdx.x;
    float acc = 0.f;
    for (int p = 0; p < np; ++p)
        acc += w_[p] * ws[WS_OP + (base + p) * HD + d];
    out[((size_t)b * NH + h) * HD + d] = acc * inv;
}

extern "C" void kernel_launch(void* const* d_in, const int* in_sizes, int n_in,
                              void* d_out, int out_size, void* d_ws, size_t ws_size,
                              hipStream_t stream) {
    const float* q    = (const float*)d_in[0];
    const float* nk   = (const float*)d_in[1];
    const float* nv   = (const float*)d_in[2];
    const float* kc   = (const float*)d_in[3];   // read-only now: no harness restore needed
    const float* vc   = (const float*)d_in[4];
    const int*   btab = (const int*)d_in[5];
    const int*   ctx  = (const int*)d_in[6];
    float* out = (float*)d_out;
    float* ws  = (float*)d_ws;

    prep<<<dim3(BATCH), dim3(128), 0, stream>>>(q, nk, ctx, ws);
    attn<<<dim3(NPART, NKVH, BATCH), dim3(256), 0, stream>>>(kc, vc, nv, ctx, btab, ws);
    attn_reduce<<<dim3(BATCH * NH), dim3(128), 0, stream>>>(ctx, ws, out);
}

// Round 3
// 491.368 us; speedup vs baseline: 1.0089x; 1.0089x over previous
//
#include <hip/hip_runtime.h>
#include <math.h>

#define BATCH 32
#define NH 32
#define NKVH 8
#define GRP 4
#define HD 128
#define BLKSZ 16
#define MAXB 128
#define PART 128
#define NPART 16
#define SCALE 0.08838834764831845f
#define NEGINF (-1e30f)

// ws layout (float elements):
#define WS_ML   0                                     // B*KVH*G*NPART*2 = 32768
#define WS_OP   (BATCH*NKVH*GRP*NPART*2)              // +B*KVH*G*NPART*HD = 2097152

// Native clang vector types: __builtin_nontemporal_load requires these
// (HIP_vector_type structs are rejected by the builtin).
typedef float f32x4 __attribute__((ext_vector_type(4)));
typedef float f32x2 __attribute__((ext_vector_type(2)));

// Single-use KV stream: bypass L2 retention with non-temporal loads.
__device__ __forceinline__ f32x4 ldnt4(const float* p) {
    return __builtin_nontemporal_load((const f32x4*)p);
}
__device__ __forceinline__ f32x2 ldnt2(const float* p) {
    return __builtin_nontemporal_load((const f32x2*)p);
}

// ---- attn: streaming flash-decode partial, rope fused in-block.
//      Tokens 0..L-2 come from the (untouched) caches; token L-1 is
//      patched in from rope(new_k)/new_v. Pure-read on all inputs. ----
__global__ __launch_bounds__(256)
void attn(const float* __restrict__ q,
          const float* __restrict__ nk,
          const float* __restrict__ nv,
          const float* __restrict__ kc,
          const float* __restrict__ vc,
          const int* __restrict__ ctx,
          const int* __restrict__ btab,
          float* __restrict__ ws)
{
    int part = blockIdx.x, kvh = blockIdx.y, b = blockIdx.z;
    int L = ctx[b];
    int start = part * PART;
    if (start >= L) return;              // reducer skips unwritten partitions
    int end = min(start + PART, L);
    int n = end - start;
    bool hasNew = (end == L);            // this partition owns token L-1
    int endC = end - (hasNew ? 1 : 0);   // cache-backed token range [start, endC)

    int tid = threadIdx.x;
    int hw = tid >> 5;                   // half-wave 0..7
    int hl = tid & 31;                   // lane in half-wave: d = 4*hl..4*hl+3
    int wave = tid >> 6, lane = tid & 63;

    __shared__ float cs[64], sn[64];     // rope tables for pos = L
    __shared__ int   bts[PART / BLKSZ];  // 8 block ids
    __shared__ float qs[GRP][HD];        // roped+scaled q, 2 KB
    __shared__ float sc[GRP][PART];      // scores -> probs, 2 KB
    __shared__ float oacc[4][GRP][HD];   // per-wave partial outputs, 8 KB

    // rope tables (wave 0) + block-table prefetch (wave 1), same math as the
    // old prep kernel so the rounding is identical.
    if (tid < 64) {
        double f = pow(10000.0, -(double)tid / 64.0);
        double a = (double)L * f;        // pos = context_lens per reference
        cs[tid] = (float)cos(a);
        sn[tid] = (float)sin(a);
    } else if (tid < 64 + PART / BLKSZ) {
        bts[tid - 64] = btab[b * MAXB + (start >> 4) + (tid - 64)];
    }
    __syncthreads();

    // rope q for this block's 4 heads into LDS (512 elems, 2 per thread)
    for (int o = tid; o < GRP * HD; o += 256) {
        int g = o >> 7, d = o & 127;
        const float* qp = q + ((size_t)b * NH + kvh * GRP + g) * HD;
        float x = qp[d], y = qp[d ^ 64];
        float c = cs[d & 63], s = sn[d & 63];
        float r = (d < 64) ? (x * c - y * s) : (x * c + y * s);
        qs[g][d] = r * SCALE;
    }
    __syncthreads();

    float4 qa[GRP];
#pragma unroll
    for (int g = 0; g < GRP; ++g)
        qa[g] = *(const float4*)(&qs[g][4 * hl]);

    const size_t koff = (size_t)kvh * HD + 4 * hl;

    // ---- Phase 1: scores from cache; 4 tokens (4 x 512B loads) in flight per half-wave ----
    int i = start + hw;
    for (; i + 24 < endC; i += 32) {
        int s0 = i, s1 = i + 8, s2 = i + 16, s3 = i + 24;
        f32x4 k0 = ldnt4(kc + ((size_t)bts[(s0 - start) >> 4] << 14) + ((s0 & 15) << 10) + koff);
        f32x4 k1 = ldnt4(kc + ((size_t)bts[(s1 - start) >> 4] << 14) + ((s1 & 15) << 10) + koff);
        f32x4 k2 = ldnt4(kc + ((size_t)bts[(s2 - start) >> 4] << 14) + ((s2 & 15) << 10) + koff);
        f32x4 k3 = ldnt4(kc + ((size_t)bts[(s3 - start) >> 4] << 14) + ((s3 & 15) << 10) + koff);
        float p0[GRP], p1[GRP], p2[GRP], p3[GRP];
#pragma unroll
        for (int g = 0; g < GRP; ++g) {
            p0[g] = qa[g].x * k0.x + qa[g].y * k0.y + qa[g].z * k0.z + qa[g].w * k0.w;
            p1[g] = qa[g].x * k1.x + qa[g].y * k1.y + qa[g].z * k1.z + qa[g].w * k1.w;
            p2[g] = qa[g].x * k2.x + qa[g].y * k2.y + qa[g].z * k2.z + qa[g].w * k2.w;
            p3[g] = qa[g].x * k3.x + qa[g].y * k3.y + qa[g].z * k3.z + qa[g].w * k3.w;
        }
#pragma unroll
        for (int off = 16; off >= 1; off >>= 1) {
#pragma unroll
            for (int g = 0; g < GRP; ++g) {
                p0[g] += __shfl_xor(p0[g], off, 32);
                p1[g] += __shfl_xor(p1[g], off, 32);
                p2[g] += __shfl_xor(p2[g], off, 32);
                p3[g] += __shfl_xor(p3[g], off, 32);
            }
        }
        if (hl == 0) {
#pragma unroll
            for (int g = 0; g < GRP; ++g) {
                sc[g][s0 - start] = p0[g];
                sc[g][s1 - start] = p1[g];
                sc[g][s2 - start] = p2[g];
                sc[g][s3 - start] = p3[g];
            }
        }
    }
    for (; i < endC; i += 8) {
        f32x4 k0 = ldnt4(kc + ((size_t)bts[(i - start) >> 4] << 14) + ((i & 15) << 10) + koff);
        float p0[GRP];
#pragma unroll
        for (int g = 0; g < GRP; ++g)
            p0[g] = qa[g].x * k0.x + qa[g].y * k0.y + qa[g].z * k0.z + qa[g].w * k0.w;
#pragma unroll
        for (int off = 16; off >= 1; off >>= 1)
#pragma unroll
            for (int g = 0; g < GRP; ++g)
                p0[g] += __shfl_xor(p0[g], off, 32);
        if (hl == 0)
#pragma unroll
            for (int g = 0; g < GRP; ++g)
                sc[g][i - start] = p0[g];
    }

    // ---- New-token score patch: sc[g][n-1] = qs[g] . rope(new_k), roped inline.
    //      Wave g owns head g; lane covers d = 2*lane, 2*lane+1. ----
    if (hasNew) {
        int g = wave;
        const float* kp = nk + ((size_t)b * NKVH + kvh) * HD;
        float p = 0.f;
#pragma unroll
        for (int u = 0; u < 2; ++u) {
            int d = 2 * lane + u;
            float x = kp[d], y = kp[d ^ 64];
            float c = cs[d & 63], s = sn[d & 63];
            float r = (d < 64) ? (x * c - y * s) : (x * c + y * s);
            p += qs[g][d] * r;
        }
#pragma unroll
        for (int off = 32; off >= 1; off >>= 1) p += __shfl_xor(p, off);
        if (lane == 0) sc[g][n - 1] = p;
    }
    __syncthreads();

    // ---- Phase 2: per-head softmax (unnormalized), wave w owns head w ----
    {
        int g = wave;
        float m = NEGINF;
        for (int j = lane; j < n; j += 64) m = fmaxf(m, sc[g][j]);
#pragma unroll
        for (int off = 32; off >= 1; off >>= 1) m = fmaxf(m, __shfl_xor(m, off));
        float sum = 0.f;
        for (int j = lane; j < n; j += 64) {
            float e = __expf(sc[g][j] - m);
            sc[g][j] = e;
            sum += e;
        }
#pragma unroll
        for (int off = 32; off >= 1; off >>= 1) sum += __shfl_xor(sum, off);
        if (lane == 0) {
            size_t mlidx = ((((size_t)b * NKVH + kvh) * GRP + g) * NPART + part) * 2;
            ws[WS_ML + mlidx]     = m;
            ws[WS_ML + mlidx + 1] = sum;
        }
    }
    __syncthreads();

    // ---- Phase 3: o += p[s]*V[s] over cache tokens; wave owns a contiguous
    //      64-token chunk, float2 per lane, 4 x 512B loads in flight ----
    float2 acc[GRP];
#pragma unroll
    for (int g = 0; g < GRP; ++g) acc[g] = make_float2(0.f, 0.f);

    const size_t voff = (size_t)kvh * HD + 2 * lane;
    int t0 = start + (wave << 6);
    int tend = min(t0 + 64, endC);
    int t = t0;
    for (; t + 3 < tend; t += 4) {
        f32x2 v0 = ldnt2(vc + ((size_t)bts[(t     - start) >> 4] << 14) + (( t      & 15) << 10) + voff);
        f32x2 v1 = ldnt2(vc + ((size_t)bts[(t + 1 - start) >> 4] << 14) + (((t + 1) & 15) << 10) + voff);
        f32x2 v2 = ldnt2(vc + ((size_t)bts[(t + 2 - start) >> 4] << 14) + (((t + 2) & 15) << 10) + voff);
        f32x2 v3 = ldnt2(vc + ((size_t)bts[(t + 3 - start) >> 4] << 14) + (((t + 3) & 15) << 10) + voff);
#pragma unroll
        for (int g = 0; g < GRP; ++g) {
            float4 e = *(const float4*)(&sc[g][t - start]);   // (t-start) % 4 == 0
            acc[g].x += e.x * v0.x; acc[g].y += e.x * v0.y;
            acc[g].x += e.y * v1.x; acc[g].y += e.y * v1.y;
            acc[g].x += e.z * v2.x; acc[g].y += e.z * v2.y;
            acc[g].x += e.w * v3.x; acc[g].y += e.w * v3.y;
        }
    }
    for (; t < tend; ++t) {
        f32x2 v0 = ldnt2(vc + ((size_t)bts[(t - start) >> 4] << 14) + ((t & 15) << 10) + voff);
#pragma unroll
        for (int g = 0; g < GRP; ++g) {
            float e = sc[g][t - start];
            acc[g].x += e * v0.x; acc[g].y += e * v0.y;
        }
    }
    // ---- New-token V patch: acc += p[L-1] * new_v, on the wave owning that chunk ----
    if (hasNew && wave == ((n - 1) >> 6)) {
        float2 v = *(const float2*)(nv + ((size_t)b * NKVH + kvh) * HD + 2 * lane);
#pragma unroll
        for (int g = 0; g < GRP; ++g) {
            float e = sc[g][n - 1];
            acc[g].x += e * v.x; acc[g].y += e * v.y;
        }
    }
#pragma unroll
    for (int g = 0; g < GRP; ++g)
        *(float2*)&oacc[wave][g][2 * lane] = acc[g];
    __syncthreads();

    for (int o = tid; o < GRP * HD; o += 256) {
        int g = o >> 7, d = o & 127;
        float ssum = oacc[0][g][d] + oacc[1][g][d] + oacc[2][g][d] + oacc[3][g][d];
        ws[WS_OP + ((((size_t)b * NKVH + kvh) * GRP + g) * NPART + part) * HD + d] = ssum;
    }
}

__global__ __launch_bounds__(128)
void attn_reduce(const int* __restrict__ ctx,
                 const float* __restrict__ ws,
                 float* __restrict__ out) {
    int bh = blockIdx.x;
    int b = bh >> 5;
    int h = bh & 31;
    int kvh = h >> 2, g = h & 3;
    int L = ctx[b];
    int np = min(NPART, (L + PART - 1) / PART);
    size_t base = (((size_t)b * NKVH + kvh) * GRP + g) * NPART;
    float M = NEGINF;
#pragma unroll 4
    for (int p = 0; p < np; ++p)
        M = fmaxf(M, ws[WS_ML + (base + p) * 2]);
    float w_[NPART];
    float Lsum = 0.f;
#pragma unroll 4
    for (int p = 0; p < np; ++p) {
        float e = __expf(ws[WS_ML + (base + p) * 2] - M);
        w_[p] = e;
        Lsum += e * ws[WS_ML + (base + p) * 2 + 1];
    }
    float inv = 1.0f / Lsum;
    int d = threadIdx.x;
    float acc = 0.f;
#pragma unroll 4
    for (int p = 0; p < np; ++p)
        acc += w_[p] * ws[WS_OP + (base + p) * HD + d];
    out[((size_t)b * NH + h) * HD + d] = acc * inv;
}

extern "C" void kernel_launch(void* const* d_in, const int* in_sizes, int n_in,
                              void* d_out, int out_size, void* d_ws, size_t ws_size,
                              hipStream_t stream) {
    const float* q    = (const float*)d_in[0];
    const float* nk   = (const float*)d_in[1];
    const float* nv   = (const float*)d_in[2];
    const float* kc   = (const float*)d_in[3];   // read-only: caches never mutated
    const float* vc   = (const float*)d_in[4];
    const int*   btab = (const int*)d_in[5];
    const int*   ctx  = (const int*)d_in[6];
    float* out = (float*)d_out;
    float* ws  = (float*)d_ws;

    attn<<<dim3(NPART, NKVH, BATCH), dim3(256), 0, stream>>>(q, nk, nv, kc, vc, ctx, btab, ws);
    attn_reduce<<<dim3(BATCH * NH), dim3(128), 0, stream>>>(ctx, ws, out);
}